// Round 12
// baseline (186.440 us; speedup 1.0000x reference)
//
#include <hip/hip_runtime.h>

#define EPSV 1e-7f

typedef __bf16 bf16x8 __attribute__((ext_vector_type(8)));
typedef float  f32x4  __attribute__((ext_vector_type(4)));
typedef unsigned int   u32x4 __attribute__((ext_vector_type(4)));
typedef unsigned short u16x8 __attribute__((ext_vector_type(8)));
typedef unsigned short u16x4 __attribute__((ext_vector_type(4)));

// ---- rne bf16 (setup paths) ----
__device__ __forceinline__ unsigned short f2bf(float f) {
    unsigned int u = __float_as_uint(f);
    return (unsigned short)((u + 0x7FFFu + ((u >> 16) & 1u)) >> 16);
}
__device__ __forceinline__ float bf2f(unsigned short u) {
    return __uint_as_float(((unsigned int)u) << 16);
}
__device__ __forceinline__ void split2(float f, unsigned short& hi, unsigned short& lo) {
    hi = f2bf(f);
    lo = f2bf(f - bf2f(hi));
}
// ---- truncation split (hot path) ----
__device__ __forceinline__ void splitT(float f, unsigned short& hi, unsigned short& lo) {
    unsigned int u  = __float_as_uint(f);
    unsigned int hb = u & 0xFFFF0000u;
    float l = f - __uint_as_float(hb);
    hi = (unsigned short)(u >> 16);
    lo = (unsigned short)(__float_as_uint(l) >> 16);
}
// pack hi-bf16(trunc) of two f32 into one u32 (elem a -> low half)
__device__ __forceinline__ unsigned int packhi2(float a, float b) {
    return (__float_as_uint(b) & 0xFFFF0000u) | (__float_as_uint(a) >> 16);
}
__device__ __forceinline__ float sigf(float x) {
    return __builtin_amdgcn_rcpf(1.0f + __expf(-x));
}
__device__ __forceinline__ float tanhfast(float x) {
    float cx = fminf(fmaxf(x, -15.0f), 15.0f);
    float e = __expf(2.0f * cx);
    return (e - 1.0f) * __builtin_amdgcn_rcpf(e + 1.0f);
}
__device__ __forceinline__ float xor8(float v) {
    return __builtin_bit_cast(float, __builtin_amdgcn_update_dpp(
        0, __builtin_bit_cast(int, v), 0x128, 0xF, 0xF, true));
}

#define MFMA16(A, B, C) __builtin_amdgcn_mfma_f32_16x16x32_bf16(A, B, C, 0, 0, 0)
#define BC8(x) __builtin_bit_cast(bf16x8, x)

// LDS-only workgroup barrier (no vmcnt drain; prefetch floats across)
#define BARRIER() do {                                        \
    asm volatile("s_waitcnt lgkmcnt(0)" ::: "memory");        \
    __builtin_amdgcn_s_barrier();                             \
    __builtin_amdgcn_sched_barrier(0);                        \
} while (0)

#define HS2 72    // hbuf row stride (u16): h_hi[0..31] h_lo[32..63] pad
#define MS  136   // mlps/hids row stride (u16)
#define XS2 136   // xbuf row stride (u16)
#define ZS3 20    // zx col stride (f32)

// 512 threads = 8 waves, 16 batch rows, grid 256 -> 2 waves/SIMD.
// A (waves 0-3): recurrent critical path (encoder h-hi only); decoder cn/fc
//   staging in A's idle slot.
// B (waves 4-7): encoder x@K producer (x-hi-only, depth-3 prefetch ring);
//   decoder xn staging + mlp1 + mlp2 + latest + out.
__global__ __launch_bounds__(512) void tutina_kernel(
    const float* __restrict__ history, const float* __restrict__ control,
    const float* __restrict__ forecasts,
    const float* __restrict__ h_mean, const float* __restrict__ h_var,
    const float* __restrict__ c_mean, const float* __restrict__ c_var,
    const float* __restrict__ f_mean, const float* __restrict__ f_var,
    const float* __restrict__ conv_w, const float* __restrict__ conv_b,
    const float* __restrict__ lstm_k, const float* __restrict__ lstm_rk,
    const float* __restrict__ lstm_b,
    const float* __restrict__ w1, const float* __restrict__ b1,
    const float* __restrict__ w2, const float* __restrict__ b2,
    float* __restrict__ out)
{
    __shared__ unsigned short hbuf[2][16 * HS2];   // h, ping-pong
    __shared__ float zxb[2][4][2][16 * ZS3];       // x@K partials (encoder)
    __shared__ unsigned short xbuf[16 * XS2];      // decoder xn staging
    __shared__ unsigned short mlps[16 * MS];       // MLP cat staging
    __shared__ unsigned short hids[16 * MS];       // MLP hidden staging
    __shared__ unsigned int   fcs[48 * 64];        // fc conv, packed (hi<<16)|lo

    const int tid  = threadIdx.x;
    const int lane = tid & 63;
    const int wid  = tid >> 6;      // 0..7
    const int wa   = wid & 3;       // role-local wave index
    const bool gA  = (wid < 4);
    const int lt   = tid & 255;     // group-local thread id
    const int l15  = lane & 15;
    const int l4   = lane >> 4;
    const int b0   = blockIdx.x * 16;

    const f32x4 zero4 = {0.f, 0.f, 0.f, 0.f};

    for (int i = tid; i < 16 * HS2; i += 512) hbuf[0][i] = 0;
    for (int i = tid; i < 16 * MS;  i += 512) mlps[i] = 0;

    const int  uu     = l15 & 7;
    const bool lohalf = (l15 < 8);
    const int  u      = wa * 8 + uu;
    const int  jz0    = lohalf ? u      : 32 + u;
    const int  jz1    = lohalf ? 64 + u : 96 + u;
    const int  j1     = wa * 16 + l15;

    // ---- fragment builders ----
    auto bfragK = [&](int kbase, int j, float& dacc, bf16x8& H, bf16x8& L) {
        u16x8 h, l;
#pragma unroll
        for (int i = 0; i < 8; i++) {
            int k = kbase + l4 * 8 + i;
            float sv = 1.0f / fmaxf(sqrtf(h_var[k]), EPSV);
            float w  = lstm_k[k * 128 + j] * sv;
            dacc += h_mean[k] * w;
            unsigned short hh, ll; split2(w, hh, ll);
            h[i] = hh; l[i] = ll;
        }
        H = BC8(h); L = BC8(l);
    };
    auto bfragP = [&](const float* W, int ldw, int kbase, int j, bf16x8& H, bf16x8& L) {
        u16x8 h, l;
#pragma unroll
        for (int i = 0; i < 8; i++) {
            int k = kbase + l4 * 8 + i;
            float w = W[k * ldw + j];
            unsigned short hh, ll; split2(w, hh, ll);
            h[i] = hh; l[i] = ll;
        }
        H = BC8(h); L = BC8(l);
    };
    auto bfragW11 = [&](int j, float& dacc, bf16x8& H, bf16x8& L) {
        u16x8 h, l;
#pragma unroll
        for (int i = 0; i < 8; i++) {
            int k = 32 + l4 * 8 + i;
            float w = 0.0f;
            if (k < 52) {
                w = w1[k * 64 + j];
                if (k < 48) {
                    float sv = 1.0f / fmaxf(sqrtf(c_var[k - 32]), EPSV);
                    w *= sv;
                    dacc += c_mean[k - 32] * w;
                }
            }
            unsigned short hh, ll; split2(w, hh, ll);
            h[i] = hh; l[i] = ll;
        }
        H = BC8(h); L = BC8(l);
    };

    // ---- K x-frags (B: zx producer; A: decoder z) ----
    bf16x8 fA0h, fA0l, fA1h, fA1l, fB0h, fB0l, fB1h, fB1l;
    float dz0 = 0.f, dz1 = 0.f;
    bfragK(0,  jz0, dz0, fA0h, fA0l);
    bfragK(32, jz0, dz0, fA1h, fA1l);
    bfragK(0,  jz1, dz1, fB0h, fB0l);
    bfragK(32, jz1, dz1, fB1h, fB1l);

    // ---- A: recurrent frags + gate biases + control reg ----
    bf16x8 fA2h, fA2l, fB2h, fB2l;
    float bi_ = 0.f, bf_ = 0.f, bg_ = 0.f, bo_ = 0.f;
    f32x4 creg = {0.f, 0.f, 0.f, 0.f};
    const int rc = lt >> 2, cc = (lt & 3) * 4;
    if (gA) {
        bfragP(lstm_rk, 128, 0, jz0, fA2h, fA2l);
        bfragP(lstm_rk, 128, 0, jz1, fB2h, fB2l);
        float z0s = dz0, z1s = dz1;
        z0s += __shfl_xor(z0s, 16, 64); z0s += __shfl_xor(z0s, 32, 64);
        z1s += __shfl_xor(z1s, 16, 64); z1s += __shfl_xor(z1s, 32, 64);
        float pd0 = xor8(z0s), pd1 = xor8(z1s);
        bi_ = lstm_b[u]      - (lohalf ? z0s : pd0);
        bf_ = lstm_b[32 + u] - (lohalf ? pd0 : z0s);
        bg_ = lstm_b[64 + u] - (lohalf ? z1s : pd1);
        bo_ = lstm_b[96 + u] - (lohalf ? pd1 : z1s);
        if (lt < 64)   // A-wave 0 owns control staging
            creg = *(const f32x4*)(control + ((size_t)(b0 + rc) * 48 + 0) * 16 + cc);
    }

    // ---- B: MLP frags, latest, fc conv ----
    bf16x8 fW10h, fW10l, fW11h, fW11l, fW20h, fW20l, fW21h, fW21l;
    float b1j = 0.f, b2j = 0.f;
    float lat0 = 0.f, lat1 = 0.f, lat2 = 0.f, lat3 = 0.f;
    if (!gA) {
        bfragP(w1, 64, 0, j1, fW10h, fW10l);
        float d1 = 0.f;
        bfragW11(j1, d1, fW11h, fW11l);
        bfragP(w2, 64, 0,  j1, fW20h, fW20l);
        bfragP(w2, 64, 32, j1, fW21h, fW21l);
        d1 += __shfl_xor(d1, 16, 64); d1 += __shfl_xor(d1, 32, 64);
        b1j = b1[j1] - d1;
        b2j = b2[j1];
        lat0 = history[((size_t)(b0 + l4 * 4 + 0) * 168 + 167) * 64 + j1];
        lat1 = history[((size_t)(b0 + l4 * 4 + 1) * 168 + 167) * 64 + j1];
        lat2 = history[((size_t)(b0 + l4 * 4 + 2) * 168 + 167) * 64 + j1];
        lat3 = history[((size_t)(b0 + l4 * 4 + 3) * 168 + 167) * 64 + j1];
        float fm  = f_mean[0];
        float fsc = 1.0f / fmaxf(sqrtf(f_var[0]), EPSV);
        for (int cell = lt; cell < 48 * 64; cell += 256) {
            int t  = cell >> 6;
            int b  = (cell >> 2) & 15;
            int uc = cell & 3;
            const float* fp = forecasts + ((size_t)(b0 + b) * 49 + t) * 8;
            float acc = conv_b[uc];
#pragma unroll
            for (int k = 0; k < 8; k++) {
                acc += (fp[k]     - fm) * fsc * conv_w[k * 4 + uc];
                acc += (fp[8 + k] - fm) * fsc * conv_w[32 + k * 4 + uc];
            }
            unsigned short hh, ll; split2(acc, hh, ll);
            fcs[cell] = ((unsigned int)hh << 16) | ll;
        }
    }

    const int r0 = l4 * 4 + (lohalf ? 0 : 2);
    const int r1 = r0 + 1;
    float c0 = 0.0f, c1 = 0.0f;

    // ---- gates (A): DPP xor8 exchange; h-hi always, lo/mlp optional ----
    auto lstm_gates = [&](const f32x4& a, const f32x4& b, unsigned short* hw,
                          bool write_lo, bool write_mlp) {
        float sa0 = lohalf ? a[2] : a[0];
        float sa1 = lohalf ? a[3] : a[1];
        float sb0 = lohalf ? b[2] : b[0];
        float sb1 = lohalf ? b[3] : b[1];
        float ra0 = xor8(sa0);
        float ra1 = xor8(sa1);
        float rb0 = xor8(sb0);
        float rb1 = xor8(sb1);
        float zi0 = (lohalf ? a[0] : ra0) + bi_;
        float zi1 = (lohalf ? a[1] : ra1) + bi_;
        float zf0 = (lohalf ? ra0 : a[2]) + bf_;
        float zf1 = (lohalf ? ra1 : a[3]) + bf_;
        float zg0 = (lohalf ? b[0] : rb0) + bg_;
        float zg1 = (lohalf ? b[1] : rb1) + bg_;
        float zo0 = (lohalf ? rb0 : b[2]) + bo_;
        float zo1 = (lohalf ? rb1 : b[3]) + bo_;
        c0 = sigf(zf0) * c0 + sigf(zi0) * tanhfast(zg0);
        c1 = sigf(zf1) * c1 + sigf(zi1) * tanhfast(zg1);
        float h20 = sigf(zo0) * tanhfast(c0);
        float h21 = sigf(zo1) * tanhfast(c1);
        unsigned short bh, bl;
        splitT(h20, bh, bl);
        hw[r0 * HS2 + u] = bh;
        if (write_lo)  hw[r0 * HS2 + 32 + u] = bl;
        if (write_mlp) { mlps[r0 * MS + u] = bh; mlps[r0 * MS + 64 + u] = bl; }
        splitT(h21, bh, bl);
        hw[r1 * HS2 + u] = bh;
        if (write_lo)  hw[r1 * HS2 + 32 + u] = bl;
        if (write_mlp) { mlps[r1 * MS + u] = bh; mlps[r1 * MS + 64 + u] = bl; }
    };

    // ---- B encoder: x-hi-only frags (pure bit-pack) + x@K (8 MFMA) ----
    auto mk_frags_hi = [&](const f32x4& p0, const f32x4& p1, const f32x4& p2,
                           const f32x4& p3, bf16x8& A0h, bf16x8& A1h) {
        u32x4 w0, w1;
        w0[0] = packhi2(p0[0], p0[1]); w0[1] = packhi2(p0[2], p0[3]);
        w0[2] = packhi2(p1[0], p1[1]); w0[3] = packhi2(p1[2], p1[3]);
        w1[0] = packhi2(p2[0], p2[1]); w1[1] = packhi2(p2[2], p2[3]);
        w1[2] = packhi2(p3[0], p3[1]); w1[3] = packhi2(p3[2], p3[3]);
        A0h = BC8(w0); A1h = BC8(w1);
    };
    auto zx12_hi = [&](bf16x8 A0h, bf16x8 A1h, f32x4& zn0, f32x4& zn1) {
        f32x4 s0 = zero4, s1 = zero4;
        s0 = MFMA16(A0h, fA0h, s0);  s1 = MFMA16(A0h, fB0h, s1);
        s0 = MFMA16(A1h, fA1h, s0);  s1 = MFMA16(A1h, fB1h, s1);
        s0 = MFMA16(A0h, fA0l, s0);  s1 = MFMA16(A0h, fB0l, s1);
        s0 = MFMA16(A1h, fA1l, s0);  s1 = MFMA16(A1h, fB1l, s1);
        zn0 = s0; zn1 = s1;
    };

    // ---- encoder prologue (B): zx[0]; depth-3 x prefetch ring ----
    const float* hp = history + (size_t)(b0 + l15) * (168 * 64);
    const int o1 = l4 * 8, o2 = 32 + l4 * 8;
    const int zoff = l15 * ZS3 + l4 * 4;
    f32x4 x1a, x1b, x1c, x1d;   // x_{t+1}
    f32x4 x2a, x2b, x2c, x2d;   // x_{t+2}
    f32x4 x3a, x3b, x3c, x3d;   // x_{t+3}
    if (!gA) {
        f32x4 p0 = *(const f32x4*)(hp + o1), p1 = *(const f32x4*)(hp + o1 + 4);
        f32x4 p2 = *(const f32x4*)(hp + o2), p3 = *(const f32x4*)(hp + o2 + 4);
        bf16x8 A0h, A1h;
        mk_frags_hi(p0, p1, p2, p3, A0h, A1h);
        f32x4 zn0, zn1;
        zx12_hi(A0h, A1h, zn0, zn1);
        *(f32x4*)&zxb[0][wa][0][zoff] = zn0;
        *(f32x4*)&zxb[0][wa][1][zoff] = zn1;
        x1a = *(const f32x4*)(hp + 64 + o1);  x1b = *(const f32x4*)(hp + 64 + o1 + 4);
        x1c = *(const f32x4*)(hp + 64 + o2);  x1d = *(const f32x4*)(hp + 64 + o2 + 4);
        x2a = *(const f32x4*)(hp + 128 + o1); x2b = *(const f32x4*)(hp + 128 + o1 + 4);
        x2c = *(const f32x4*)(hp + 128 + o2); x2d = *(const f32x4*)(hp + 128 + o2 + 4);
        x3a = *(const f32x4*)(hp + 192 + o1); x3b = *(const f32x4*)(hp + 192 + o1 + 4);
        x3c = *(const f32x4*)(hp + 192 + o2); x3d = *(const f32x4*)(hp + 192 + o2 + 4);
    }
    if (gA) __builtin_amdgcn_s_setprio(1);
    BARRIER();

    // ---- encoder: 168 steps, 1 barrier each ----
    for (int t = 0; t < 168; ++t) {
        const int p = t & 1;
        if (gA) {
            const unsigned short* hr = hbuf[p];
            bf16x8 a2h = BC8(*(const u32x4*)&hr[l15 * HS2 + l4 * 8]);
            f32x4 zx0 = *(const f32x4*)&zxb[p][wa][0][zoff];
            f32x4 zx1 = *(const f32x4*)&zxb[p][wa][1][zoff];
            // depth-1 chains: all four MFMAs start as soon as a2h is ready
            f32x4 z0  = MFMA16(a2h, fA2h, zx0);
            f32x4 z1  = MFMA16(a2h, fB2h, zx1);
            f32x4 z0l = MFMA16(a2h, fA2l, zero4);
            f32x4 z1l = MFMA16(a2h, fB2l, zero4);
            z0 += z0l; z1 += z1l;
            lstm_gates(z0, z1, hbuf[p ^ 1], t == 167, t == 167);
        } else {
            bf16x8 A0h, A1h;
            mk_frags_hi(x1a, x1b, x1c, x1d, A0h, A1h);
            // rotate ring, issue load for x_{t+4} (3 steps in flight)
            x1a = x2a; x1b = x2b; x1c = x2c; x1d = x2d;
            x2a = x3a; x2b = x3b; x2c = x3c; x2d = x3d;
            const float* np = hp + (size_t)((t + 4 < 168) ? t + 4 : 167) * 64;
            x3a = *(const f32x4*)(np + o1); x3b = *(const f32x4*)(np + o1 + 4);
            x3c = *(const f32x4*)(np + o2); x3d = *(const f32x4*)(np + o2 + 4);
            f32x4 zn0, zn1;
            zx12_hi(A0h, A1h, zn0, zn1);
            *(f32x4*)&zxb[p ^ 1][wa][0][zoff] = zn0;
            *(f32x4*)&zxb[p ^ 1][wa][1][zoff] = zn1;
        }
        BARRIER();
    }
    // h_168 (hi+lo) in hbuf[0] and mlps.h

    // ---- staging + MLP helpers ----
    auto stage_cn = [&](const f32x4& v) {
        if (lt < 64) {
            u16x4 oh, ol;
#pragma unroll
            for (int q = 0; q < 4; q++) {
                unsigned short hh, ll;
                splitT(v[q], hh, ll);
                oh[q] = hh; ol[q] = ll;
            }
            *(u16x4*)&mlps[rc * MS + 32 + cc]      = oh;
            *(u16x4*)&mlps[rc * MS + 64 + 32 + cc] = ol;
        }
    };
    auto stage_fc = [&](int t) {
        if (lt >= 64 && lt < 128) {
            int q = lt - 64;
            unsigned int v = fcs[t * 64 + q];
            mlps[(q >> 2) * MS + 48 + (q & 3)]      = (unsigned short)(v >> 16);
            mlps[(q >> 2) * MS + 64 + 48 + (q & 3)] = (unsigned short)(v & 0xFFFFu);
        }
    };
    auto mlp1 = [&]() {   // B
        const int mbase = l15 * MS + l4 * 8;
        bf16x8 m0  = BC8(*(const u32x4*)&mlps[mbase]);
        bf16x8 m1  = BC8(*(const u32x4*)&mlps[mbase + 32]);
        bf16x8 m0l = BC8(*(const u32x4*)&mlps[mbase + 64]);
        bf16x8 m1l = BC8(*(const u32x4*)&mlps[mbase + 96]);
        f32x4 ha = zero4, hb = zero4;
        ha = MFMA16(m0,  fW10h, ha);   hb = MFMA16(m1,  fW11h, hb);
        ha = MFMA16(m0l, fW10h, ha);   hb = MFMA16(m1l, fW11h, hb);
        ha = MFMA16(m0,  fW10l, ha);   hb = MFMA16(m1,  fW11l, hb);
        f32x4 hacc = ha + hb;
#pragma unroll
        for (int q = 0; q < 4; q++) {
            float hv = fmaxf(hacc[q] + b1j, 0.0f);
            unsigned short hh, ll;
            splitT(hv, hh, ll);
            hids[(l4 * 4 + q) * MS + j1]      = hh;
            hids[(l4 * 4 + q) * MS + 64 + j1] = ll;
        }
    };
    auto mlp2 = [&]() {   // B
        const int mbase = l15 * MS + l4 * 8;
        bf16x8 h0  = BC8(*(const u32x4*)&hids[mbase]);
        bf16x8 h1  = BC8(*(const u32x4*)&hids[mbase + 32]);
        bf16x8 h0l = BC8(*(const u32x4*)&hids[mbase + 64]);
        bf16x8 h1l = BC8(*(const u32x4*)&hids[mbase + 96]);
        f32x4 oa = zero4, ob = zero4;
        oa = MFMA16(h0,  fW20h, oa);   ob = MFMA16(h1,  fW21h, ob);
        oa = MFMA16(h0l, fW20h, oa);   ob = MFMA16(h1l, fW21h, ob);
        oa = MFMA16(h0,  fW20l, oa);   ob = MFMA16(h1,  fW21l, ob);
        f32x4 oacc = oa + ob;
        lat0 += oacc[0] + b2j;
        lat1 += oacc[1] + b2j;
        lat2 += oacc[2] + b2j;
        lat3 += oacc[3] + b2j;
    };

    // ---- post-encoder MLP: latest += mlp(h_enc, cn_0, fc_0) ----
    if (gA) { stage_cn(creg); stage_fc(0); }
    BARRIER();
    if (!gA) mlp1();
    BARRIER();
    if (!gA) mlp2();
    // A prefetches control slice 1 for decoder-iter-0 bottom staging
    if (gA && lt < 64)
        creg = *(const f32x4*)(control + ((size_t)(b0 + rc) * 48 + 1) * 16 + cc);

    // ---- decoder: 48 steps, 3 barriers each ----
    // cn/fc slice t staged by A at bottom of iter t-1 (slice 0 survives from
    // post-encoder staging; gates touch only the h-region of mlps).
    for (int t = 0; t < 48; ++t) {
        const int p = t & 1;
        if (!gA) {
            // xn = lat (raw; norm folded into K) -> xbuf (full hi/lo)
            unsigned short bh, bl;
            splitT(lat0, bh, bl);
            xbuf[(l4 * 4 + 0) * XS2 + j1] = bh; xbuf[(l4 * 4 + 0) * XS2 + 64 + j1] = bl;
            splitT(lat1, bh, bl);
            xbuf[(l4 * 4 + 1) * XS2 + j1] = bh; xbuf[(l4 * 4 + 1) * XS2 + 64 + j1] = bl;
            splitT(lat2, bh, bl);
            xbuf[(l4 * 4 + 2) * XS2 + j1] = bh; xbuf[(l4 * 4 + 2) * XS2 + 64 + j1] = bl;
            splitT(lat3, bh, bl);
            xbuf[(l4 * 4 + 3) * XS2 + j1] = bh; xbuf[(l4 * 4 + 3) * XS2 + 64 + j1] = bl;
        }
        BARRIER();   // B1: xn + (cn/fc from iter t-1 bottom) staged

        if (gA) {
            const unsigned short* hr = hbuf[p];
            const int xb = l15 * XS2 + l4 * 8;
            bf16x8 a0h = BC8(*(const u32x4*)&xbuf[xb]);
            bf16x8 a1h = BC8(*(const u32x4*)&xbuf[xb + 32]);
            bf16x8 a0l = BC8(*(const u32x4*)&xbuf[xb + 64]);
            bf16x8 a1l = BC8(*(const u32x4*)&xbuf[xb + 96]);
            bf16x8 a2h = BC8(*(const u32x4*)&hr[l15 * HS2 + l4 * 8]);
            bf16x8 a2l = BC8(*(const u32x4*)&hr[l15 * HS2 + 32 + l4 * 8]);
            f32x4 z0a = zero4, z0b = zero4;
            f32x4 z1a = zero4, z1b = zero4;
            z0a = MFMA16(a0h, fA0h, z0a);  z1a = MFMA16(a0h, fB0h, z1a);
            z0b = MFMA16(a1h, fA1h, z0b);  z1b = MFMA16(a1h, fB1h, z1b);
            z0a = MFMA16(a2h, fA2h, z0a);  z1a = MFMA16(a2h, fB2h, z1a);
            z0b = MFMA16(a0l, fA0h, z0b);  z1b = MFMA16(a0l, fB0h, z1b);
            z0a = MFMA16(a1l, fA1h, z0a);  z1a = MFMA16(a1l, fB1h, z1a);
            z0b = MFMA16(a2l, fA2h, z0b);  z1b = MFMA16(a2l, fB2h, z1b);
            z0a = MFMA16(a0h, fA0l, z0a);  z1a = MFMA16(a0h, fB0l, z1a);
            z0b = MFMA16(a1h, fA1l, z0b);  z1b = MFMA16(a1h, fB1l, z1b);
            z0a = MFMA16(a2h, fA2l, z0a);  z1a = MFMA16(a2h, fB2l, z1a);
            f32x4 z0 = z0a + z0b, z1 = z1a + z1b;
            lstm_gates(z0, z1, hbuf[p ^ 1], true, true);
        }
        BARRIER();   // B2: h_t + mlps.h visible

        if (!gA) mlp1();
        BARRIER();   // B3: hids visible

        if (!gA) {
            mlp2();
            out[((size_t)(b0 + l4 * 4 + 0) * 48 + t) * 64 + j1] = lat0;
            out[((size_t)(b0 + l4 * 4 + 1) * 48 + t) * 64 + j1] = lat1;
            out[((size_t)(b0 + l4 * 4 + 2) * 48 + t) * 64 + j1] = lat2;
            out[((size_t)(b0 + l4 * 4 + 3) * 48 + t) * 64 + j1] = lat3;
        } else {
            // A idle slot: stage cn/fc for iter t+1; prefetch control t+2
            int tn = (t < 47) ? t + 1 : 47;
            stage_cn(creg);
            stage_fc(tn);
            int tn2 = (t < 46) ? t + 2 : 47;
            if (lt < 64)
                creg = *(const f32x4*)(control + ((size_t)(b0 + rc) * 48 + tn2) * 16 + cc);
        }
    }
}

extern "C" void kernel_launch(void* const* d_in, const int* in_sizes, int n_in,
                              void* d_out, int out_size, void* d_ws, size_t ws_size,
                              hipStream_t stream) {
    tutina_kernel<<<dim3(256), dim3(512), 0, stream>>>(
        (const float*)d_in[0],  (const float*)d_in[1],  (const float*)d_in[2],
        (const float*)d_in[3],  (const float*)d_in[4],  (const float*)d_in[5],
        (const float*)d_in[6],  (const float*)d_in[7],  (const float*)d_in[8],
        (const float*)d_in[9],  (const float*)d_in[10], (const float*)d_in[11],
        (const float*)d_in[12], (const float*)d_in[13], (const float*)d_in[14],
        (const float*)d_in[15], (const float*)d_in[16], (const float*)d_in[17],
        (float*)d_out);
}

// Round 13
// 152.452 us; speedup vs baseline: 1.2229x; 1.2229x over previous
//
#include <hip/hip_runtime.h>

#define EPSV 1e-7f

typedef __bf16 bf16x8 __attribute__((ext_vector_type(8)));
typedef float  f32x4  __attribute__((ext_vector_type(4)));
typedef unsigned int   u32x4 __attribute__((ext_vector_type(4)));
typedef unsigned short u16x8 __attribute__((ext_vector_type(8)));
typedef unsigned short u16x4 __attribute__((ext_vector_type(4)));

// ---- rne bf16 (setup paths) ----
__device__ __forceinline__ unsigned short f2bf(float f) {
    unsigned int u = __float_as_uint(f);
    return (unsigned short)((u + 0x7FFFu + ((u >> 16) & 1u)) >> 16);
}
__device__ __forceinline__ float bf2f(unsigned short u) {
    return __uint_as_float(((unsigned int)u) << 16);
}
__device__ __forceinline__ void split2(float f, unsigned short& hi, unsigned short& lo) {
    hi = f2bf(f);
    lo = f2bf(f - bf2f(hi));
}
// ---- truncation split (hot path) ----
__device__ __forceinline__ void splitT(float f, unsigned short& hi, unsigned short& lo) {
    unsigned int u  = __float_as_uint(f);
    unsigned int hb = u & 0xFFFF0000u;
    float l = f - __uint_as_float(hb);
    hi = (unsigned short)(u >> 16);
    lo = (unsigned short)(__float_as_uint(l) >> 16);
}
// pack hi-bf16(trunc) of two f32 into one u32 (elem a -> low half)
__device__ __forceinline__ unsigned int packhi2(float a, float b) {
    return (__float_as_uint(b) & 0xFFFF0000u) | (__float_as_uint(a) >> 16);
}
__device__ __forceinline__ float sigf(float x) {
    return __builtin_amdgcn_rcpf(1.0f + __expf(-x));
}
__device__ __forceinline__ float tanhfast(float x) {
    float cx = fminf(fmaxf(x, -15.0f), 15.0f);
    float e = __expf(2.0f * cx);
    return (e - 1.0f) * __builtin_amdgcn_rcpf(e + 1.0f);
}
__device__ __forceinline__ float xor8(float v) {
    return __builtin_bit_cast(float, __builtin_amdgcn_update_dpp(
        0, __builtin_bit_cast(int, v), 0x128, 0xF, 0xF, true));
}

#define MFMA16(A, B, C) __builtin_amdgcn_mfma_f32_16x16x32_bf16(A, B, C, 0, 0, 0)
#define BC8(x) __builtin_bit_cast(bf16x8, x)

// LDS-only workgroup barrier (no vmcnt drain; prefetch floats across)
#define BARRIER() do {                                        \
    asm volatile("s_waitcnt lgkmcnt(0)" ::: "memory");        \
    __builtin_amdgcn_s_barrier();                             \
    __builtin_amdgcn_sched_barrier(0);                        \
} while (0)

#define HS2 72    // hbuf row stride (u16): h_hi[0..31] h_lo[32..63] pad
#define MS  136   // mlps/hids row stride (u16)
#define XS2 136   // xbuf row stride (u16)
#define ZS3 20    // zx col stride (f32)

// 512 threads = 8 waves, 16 batch rows, grid 256 -> 2 waves/SIMD.
// A (waves 0-3): recurrent critical path (encoder h-hi only, depth-2 chains);
//   decoder cn/fc staging in A's idle slot.
// B (waves 4-7): encoder x@K producer (x-hi-only bit-pack, 8 MFMA, 1-step
//   prefetch); decoder xn staging + mlp1 + mlp2 + latest + out.
__global__ __launch_bounds__(512) void tutina_kernel(
    const float* __restrict__ history, const float* __restrict__ control,
    const float* __restrict__ forecasts,
    const float* __restrict__ h_mean, const float* __restrict__ h_var,
    const float* __restrict__ c_mean, const float* __restrict__ c_var,
    const float* __restrict__ f_mean, const float* __restrict__ f_var,
    const float* __restrict__ conv_w, const float* __restrict__ conv_b,
    const float* __restrict__ lstm_k, const float* __restrict__ lstm_rk,
    const float* __restrict__ lstm_b,
    const float* __restrict__ w1, const float* __restrict__ b1,
    const float* __restrict__ w2, const float* __restrict__ b2,
    float* __restrict__ out)
{
    __shared__ unsigned short hbuf[2][16 * HS2];   // h, ping-pong
    __shared__ float zxb[2][4][2][16 * ZS3];       // x@K partials (encoder)
    __shared__ unsigned short xbuf[16 * XS2];      // decoder xn staging
    __shared__ unsigned short mlps[16 * MS];       // MLP cat staging
    __shared__ unsigned short hids[16 * MS];       // MLP hidden staging
    __shared__ unsigned int   fcs[48 * 64];        // fc conv, packed (hi<<16)|lo

    const int tid  = threadIdx.x;
    const int lane = tid & 63;
    const int wid  = tid >> 6;      // 0..7
    const int wa   = wid & 3;       // role-local wave index
    const bool gA  = (wid < 4);
    const int lt   = tid & 255;     // group-local thread id
    const int l15  = lane & 15;
    const int l4   = lane >> 4;
    const int b0   = blockIdx.x * 16;

    const f32x4 zero4 = {0.f, 0.f, 0.f, 0.f};

    for (int i = tid; i < 16 * HS2; i += 512) hbuf[0][i] = 0;
    for (int i = tid; i < 16 * MS;  i += 512) mlps[i] = 0;

    const int  uu     = l15 & 7;
    const bool lohalf = (l15 < 8);
    const int  u      = wa * 8 + uu;
    const int  jz0    = lohalf ? u      : 32 + u;
    const int  jz1    = lohalf ? 64 + u : 96 + u;
    const int  j1     = wa * 16 + l15;

    // ---- fragment builders ----
    auto bfragK = [&](int kbase, int j, float& dacc, bf16x8& H, bf16x8& L) {
        u16x8 h, l;
#pragma unroll
        for (int i = 0; i < 8; i++) {
            int k = kbase + l4 * 8 + i;
            float sv = 1.0f / fmaxf(sqrtf(h_var[k]), EPSV);
            float w  = lstm_k[k * 128 + j] * sv;
            dacc += h_mean[k] * w;
            unsigned short hh, ll; split2(w, hh, ll);
            h[i] = hh; l[i] = ll;
        }
        H = BC8(h); L = BC8(l);
    };
    auto bfragP = [&](const float* W, int ldw, int kbase, int j, bf16x8& H, bf16x8& L) {
        u16x8 h, l;
#pragma unroll
        for (int i = 0; i < 8; i++) {
            int k = kbase + l4 * 8 + i;
            float w = W[k * ldw + j];
            unsigned short hh, ll; split2(w, hh, ll);
            h[i] = hh; l[i] = ll;
        }
        H = BC8(h); L = BC8(l);
    };
    auto bfragW11 = [&](int j, float& dacc, bf16x8& H, bf16x8& L) {
        u16x8 h, l;
#pragma unroll
        for (int i = 0; i < 8; i++) {
            int k = 32 + l4 * 8 + i;
            float w = 0.0f;
            if (k < 52) {
                w = w1[k * 64 + j];
                if (k < 48) {
                    float sv = 1.0f / fmaxf(sqrtf(c_var[k - 32]), EPSV);
                    w *= sv;
                    dacc += c_mean[k - 32] * w;
                }
            }
            unsigned short hh, ll; split2(w, hh, ll);
            h[i] = hh; l[i] = ll;
        }
        H = BC8(h); L = BC8(l);
    };

    // ---- K x-frags (B: zx producer; A: decoder z) ----
    bf16x8 fA0h, fA0l, fA1h, fA1l, fB0h, fB0l, fB1h, fB1l;
    float dz0 = 0.f, dz1 = 0.f;
    bfragK(0,  jz0, dz0, fA0h, fA0l);
    bfragK(32, jz0, dz0, fA1h, fA1l);
    bfragK(0,  jz1, dz1, fB0h, fB0l);
    bfragK(32, jz1, dz1, fB1h, fB1l);

    // ---- A: recurrent frags + gate biases + control reg ----
    bf16x8 fA2h, fA2l, fB2h, fB2l;
    float bi_ = 0.f, bf_ = 0.f, bg_ = 0.f, bo_ = 0.f;
    f32x4 creg = {0.f, 0.f, 0.f, 0.f};
    const int rc = lt >> 2, cc = (lt & 3) * 4;
    if (gA) {
        bfragP(lstm_rk, 128, 0, jz0, fA2h, fA2l);
        bfragP(lstm_rk, 128, 0, jz1, fB2h, fB2l);
        float z0s = dz0, z1s = dz1;
        z0s += __shfl_xor(z0s, 16, 64); z0s += __shfl_xor(z0s, 32, 64);
        z1s += __shfl_xor(z1s, 16, 64); z1s += __shfl_xor(z1s, 32, 64);
        float pd0 = xor8(z0s), pd1 = xor8(z1s);
        bi_ = lstm_b[u]      - (lohalf ? z0s : pd0);
        bf_ = lstm_b[32 + u] - (lohalf ? pd0 : z0s);
        bg_ = lstm_b[64 + u] - (lohalf ? z1s : pd1);
        bo_ = lstm_b[96 + u] - (lohalf ? pd1 : z1s);
        if (lt < 64)   // A-wave 0 owns control staging
            creg = *(const f32x4*)(control + ((size_t)(b0 + rc) * 48 + 0) * 16 + cc);
    }

    // ---- B: MLP frags, latest, fc conv ----
    bf16x8 fW10h, fW10l, fW11h, fW11l, fW20h, fW20l, fW21h, fW21l;
    float b1j = 0.f, b2j = 0.f;
    float lat0 = 0.f, lat1 = 0.f, lat2 = 0.f, lat3 = 0.f;
    if (!gA) {
        bfragP(w1, 64, 0, j1, fW10h, fW10l);
        float d1 = 0.f;
        bfragW11(j1, d1, fW11h, fW11l);
        bfragP(w2, 64, 0,  j1, fW20h, fW20l);
        bfragP(w2, 64, 32, j1, fW21h, fW21l);
        d1 += __shfl_xor(d1, 16, 64); d1 += __shfl_xor(d1, 32, 64);
        b1j = b1[j1] - d1;
        b2j = b2[j1];
        lat0 = history[((size_t)(b0 + l4 * 4 + 0) * 168 + 167) * 64 + j1];
        lat1 = history[((size_t)(b0 + l4 * 4 + 1) * 168 + 167) * 64 + j1];
        lat2 = history[((size_t)(b0 + l4 * 4 + 2) * 168 + 167) * 64 + j1];
        lat3 = history[((size_t)(b0 + l4 * 4 + 3) * 168 + 167) * 64 + j1];
        float fm  = f_mean[0];
        float fsc = 1.0f / fmaxf(sqrtf(f_var[0]), EPSV);
        for (int cell = lt; cell < 48 * 64; cell += 256) {
            int t  = cell >> 6;
            int b  = (cell >> 2) & 15;
            int uc = cell & 3;
            const float* fp = forecasts + ((size_t)(b0 + b) * 49 + t) * 8;
            float acc = conv_b[uc];
#pragma unroll
            for (int k = 0; k < 8; k++) {
                acc += (fp[k]     - fm) * fsc * conv_w[k * 4 + uc];
                acc += (fp[8 + k] - fm) * fsc * conv_w[32 + k * 4 + uc];
            }
            unsigned short hh, ll; split2(acc, hh, ll);
            fcs[cell] = ((unsigned int)hh << 16) | ll;
        }
    }

    const int r0 = l4 * 4 + (lohalf ? 0 : 2);
    const int r1 = r0 + 1;
    float c0 = 0.0f, c1 = 0.0f;

    // ---- gates (A): DPP xor8 exchange; h-hi always, lo/mlp optional ----
    auto lstm_gates = [&](const f32x4& a, const f32x4& b, unsigned short* hw,
                          bool write_lo, bool write_mlp) {
        float sa0 = lohalf ? a[2] : a[0];
        float sa1 = lohalf ? a[3] : a[1];
        float sb0 = lohalf ? b[2] : b[0];
        float sb1 = lohalf ? b[3] : b[1];
        float ra0 = xor8(sa0);
        float ra1 = xor8(sa1);
        float rb0 = xor8(sb0);
        float rb1 = xor8(sb1);
        float zi0 = (lohalf ? a[0] : ra0) + bi_;
        float zi1 = (lohalf ? a[1] : ra1) + bi_;
        float zf0 = (lohalf ? ra0 : a[2]) + bf_;
        float zf1 = (lohalf ? ra1 : a[3]) + bf_;
        float zg0 = (lohalf ? b[0] : rb0) + bg_;
        float zg1 = (lohalf ? b[1] : rb1) + bg_;
        float zo0 = (lohalf ? rb0 : b[2]) + bo_;
        float zo1 = (lohalf ? rb1 : b[3]) + bo_;
        c0 = sigf(zf0) * c0 + sigf(zi0) * tanhfast(zg0);
        c1 = sigf(zf1) * c1 + sigf(zi1) * tanhfast(zg1);
        float h20 = sigf(zo0) * tanhfast(c0);
        float h21 = sigf(zo1) * tanhfast(c1);
        unsigned short bh, bl;
        splitT(h20, bh, bl);
        hw[r0 * HS2 + u] = bh;
        if (write_lo)  hw[r0 * HS2 + 32 + u] = bl;
        if (write_mlp) { mlps[r0 * MS + u] = bh; mlps[r0 * MS + 64 + u] = bl; }
        splitT(h21, bh, bl);
        hw[r1 * HS2 + u] = bh;
        if (write_lo)  hw[r1 * HS2 + 32 + u] = bl;
        if (write_mlp) { mlps[r1 * MS + u] = bh; mlps[r1 * MS + 64 + u] = bl; }
    };

    // ---- B encoder: x-hi-only frags (pure bit-pack) + x@K (8 MFMA) ----
    auto mk_frags_hi = [&](const f32x4& p0, const f32x4& p1, const f32x4& p2,
                           const f32x4& p3, bf16x8& A0h, bf16x8& A1h) {
        u32x4 w0, w1;
        w0[0] = packhi2(p0[0], p0[1]); w0[1] = packhi2(p0[2], p0[3]);
        w0[2] = packhi2(p1[0], p1[1]); w0[3] = packhi2(p1[2], p1[3]);
        w1[0] = packhi2(p2[0], p2[1]); w1[1] = packhi2(p2[2], p2[3]);
        w1[2] = packhi2(p3[0], p3[1]); w1[3] = packhi2(p3[2], p3[3]);
        A0h = BC8(w0); A1h = BC8(w1);
    };
    auto zx12_hi = [&](bf16x8 A0h, bf16x8 A1h, f32x4& zn0, f32x4& zn1) {
        f32x4 s0 = zero4, s1 = zero4;
        s0 = MFMA16(A0h, fA0h, s0);  s1 = MFMA16(A0h, fB0h, s1);
        s0 = MFMA16(A1h, fA1h, s0);  s1 = MFMA16(A1h, fB1h, s1);
        s0 = MFMA16(A0h, fA0l, s0);  s1 = MFMA16(A0h, fB0l, s1);
        s0 = MFMA16(A1h, fA1l, s0);  s1 = MFMA16(A1h, fB1l, s1);
        zn0 = s0; zn1 = s1;
    };

    // ---- encoder prologue (B): zx[0], prefetch x_1 (1-step distance) ----
    const float* hp = history + (size_t)(b0 + l15) * (168 * 64);
    const int o1 = l4 * 8, o2 = 32 + l4 * 8;
    const int zoff = l15 * ZS3 + l4 * 4;
    f32x4 vb0, vb1, vb2, vb3;
    if (!gA) {
        f32x4 p0 = *(const f32x4*)(hp + o1), p1 = *(const f32x4*)(hp + o1 + 4);
        f32x4 p2 = *(const f32x4*)(hp + o2), p3 = *(const f32x4*)(hp + o2 + 4);
        bf16x8 A0h, A1h;
        mk_frags_hi(p0, p1, p2, p3, A0h, A1h);
        f32x4 zn0, zn1;
        zx12_hi(A0h, A1h, zn0, zn1);
        *(f32x4*)&zxb[0][wa][0][zoff] = zn0;
        *(f32x4*)&zxb[0][wa][1][zoff] = zn1;
        vb0 = *(const f32x4*)(hp + 64 + o1); vb1 = *(const f32x4*)(hp + 64 + o1 + 4);
        vb2 = *(const f32x4*)(hp + 64 + o2); vb3 = *(const f32x4*)(hp + 64 + o2 + 4);
    }
    if (gA) __builtin_amdgcn_s_setprio(1);
    BARRIER();

    // ---- encoder: 168 steps, 1 barrier each ----
    for (int t = 0; t < 168; ++t) {
        const int p = t & 1;
        if (gA) {
            const unsigned short* hr = hbuf[p];
            bf16x8 a2h = BC8(*(const u32x4*)&hr[l15 * HS2 + l4 * 8]);
            f32x4 z0 = *(const f32x4*)&zxb[p][wa][0][zoff];
            f32x4 z1 = *(const f32x4*)&zxb[p][wa][1][zoff];
            z0 = MFMA16(a2h, fA2h, z0);  z1 = MFMA16(a2h, fB2h, z1);
            z0 = MFMA16(a2h, fA2l, z0);  z1 = MFMA16(a2h, fB2l, z1);
            lstm_gates(z0, z1, hbuf[p ^ 1], t == 167, t == 167);
        } else {
            bf16x8 A0h, A1h;
            mk_frags_hi(vb0, vb1, vb2, vb3, A0h, A1h);
            const float* np = hp + (size_t)((t < 166) ? t + 2 : 167) * 64;
            vb0 = *(const f32x4*)(np + o1); vb1 = *(const f32x4*)(np + o1 + 4);
            vb2 = *(const f32x4*)(np + o2); vb3 = *(const f32x4*)(np + o2 + 4);
            f32x4 zn0, zn1;
            zx12_hi(A0h, A1h, zn0, zn1);
            *(f32x4*)&zxb[p ^ 1][wa][0][zoff] = zn0;
            *(f32x4*)&zxb[p ^ 1][wa][1][zoff] = zn1;
        }
        BARRIER();
    }
    // h_168 (hi+lo) in hbuf[0] and mlps.h

    // ---- staging + MLP helpers ----
    auto stage_cn = [&](const f32x4& v) {
        if (lt < 64) {
            u16x4 oh, ol;
#pragma unroll
            for (int q = 0; q < 4; q++) {
                unsigned short hh, ll;
                splitT(v[q], hh, ll);
                oh[q] = hh; ol[q] = ll;
            }
            *(u16x4*)&mlps[rc * MS + 32 + cc]      = oh;
            *(u16x4*)&mlps[rc * MS + 64 + 32 + cc] = ol;
        }
    };
    auto stage_fc = [&](int t) {
        if (lt >= 64 && lt < 128) {
            int q = lt - 64;
            unsigned int v = fcs[t * 64 + q];
            mlps[(q >> 2) * MS + 48 + (q & 3)]      = (unsigned short)(v >> 16);
            mlps[(q >> 2) * MS + 64 + 48 + (q & 3)] = (unsigned short)(v & 0xFFFFu);
        }
    };
    auto mlp1 = [&]() {   // B
        const int mbase = l15 * MS + l4 * 8;
        bf16x8 m0  = BC8(*(const u32x4*)&mlps[mbase]);
        bf16x8 m1  = BC8(*(const u32x4*)&mlps[mbase + 32]);
        bf16x8 m0l = BC8(*(const u32x4*)&mlps[mbase + 64]);
        bf16x8 m1l = BC8(*(const u32x4*)&mlps[mbase + 96]);
        f32x4 ha = zero4, hb = zero4;
        ha = MFMA16(m0,  fW10h, ha);   hb = MFMA16(m1,  fW11h, hb);
        ha = MFMA16(m0l, fW10h, ha);   hb = MFMA16(m1l, fW11h, hb);
        ha = MFMA16(m0,  fW10l, ha);   hb = MFMA16(m1,  fW11l, hb);
        f32x4 hacc = ha + hb;
#pragma unroll
        for (int q = 0; q < 4; q++) {
            float hv = fmaxf(hacc[q] + b1j, 0.0f);
            unsigned short hh, ll;
            splitT(hv, hh, ll);
            hids[(l4 * 4 + q) * MS + j1]      = hh;
            hids[(l4 * 4 + q) * MS + 64 + j1] = ll;
        }
    };
    auto mlp2 = [&]() {   // B
        const int mbase = l15 * MS + l4 * 8;
        bf16x8 h0  = BC8(*(const u32x4*)&hids[mbase]);
        bf16x8 h1  = BC8(*(const u32x4*)&hids[mbase + 32]);
        bf16x8 h0l = BC8(*(const u32x4*)&hids[mbase + 64]);
        bf16x8 h1l = BC8(*(const u32x4*)&hids[mbase + 96]);
        f32x4 oa = zero4, ob = zero4;
        oa = MFMA16(h0,  fW20h, oa);   ob = MFMA16(h1,  fW21h, ob);
        oa = MFMA16(h0l, fW20h, oa);   ob = MFMA16(h1l, fW21h, ob);
        oa = MFMA16(h0,  fW20l, oa);   ob = MFMA16(h1,  fW21l, ob);
        f32x4 oacc = oa + ob;
        lat0 += oacc[0] + b2j;
        lat1 += oacc[1] + b2j;
        lat2 += oacc[2] + b2j;
        lat3 += oacc[3] + b2j;
    };

    // ---- post-encoder MLP: latest += mlp(h_enc, cn_0, fc_0) ----
    if (gA) { stage_cn(creg); stage_fc(0); }
    BARRIER();
    if (!gA) mlp1();
    BARRIER();
    if (!gA) mlp2();
    // A prefetches control slice 1 for decoder-iter-0 bottom staging
    if (gA && lt < 64)
        creg = *(const f32x4*)(control + ((size_t)(b0 + rc) * 48 + 1) * 16 + cc);

    // ---- decoder: 48 steps, 3 barriers each ----
    // cn/fc slice t staged by A at bottom of iter t-1 (slice 0 survives from
    // post-encoder staging; gates touch only the h-region of mlps).
    for (int t = 0; t < 48; ++t) {
        const int p = t & 1;
        if (!gA) {
            // xn = lat (raw; norm folded into K) -> xbuf (full hi/lo)
            unsigned short bh, bl;
            splitT(lat0, bh, bl);
            xbuf[(l4 * 4 + 0) * XS2 + j1] = bh; xbuf[(l4 * 4 + 0) * XS2 + 64 + j1] = bl;
            splitT(lat1, bh, bl);
            xbuf[(l4 * 4 + 1) * XS2 + j1] = bh; xbuf[(l4 * 4 + 1) * XS2 + 64 + j1] = bl;
            splitT(lat2, bh, bl);
            xbuf[(l4 * 4 + 2) * XS2 + j1] = bh; xbuf[(l4 * 4 + 2) * XS2 + 64 + j1] = bl;
            splitT(lat3, bh, bl);
            xbuf[(l4 * 4 + 3) * XS2 + j1] = bh; xbuf[(l4 * 4 + 3) * XS2 + 64 + j1] = bl;
        }
        BARRIER();   // B1: xn + (cn/fc from iter t-1 bottom) staged

        if (gA) {
            const unsigned short* hr = hbuf[p];
            const int xb = l15 * XS2 + l4 * 8;
            bf16x8 a0h = BC8(*(const u32x4*)&xbuf[xb]);
            bf16x8 a1h = BC8(*(const u32x4*)&xbuf[xb + 32]);
            bf16x8 a0l = BC8(*(const u32x4*)&xbuf[xb + 64]);
            bf16x8 a1l = BC8(*(const u32x4*)&xbuf[xb + 96]);
            bf16x8 a2h = BC8(*(const u32x4*)&hr[l15 * HS2 + l4 * 8]);
            bf16x8 a2l = BC8(*(const u32x4*)&hr[l15 * HS2 + 32 + l4 * 8]);
            f32x4 z0a = zero4, z0b = zero4;
            f32x4 z1a = zero4, z1b = zero4;
            z0a = MFMA16(a0h, fA0h, z0a);  z1a = MFMA16(a0h, fB0h, z1a);
            z0b = MFMA16(a1h, fA1h, z0b);  z1b = MFMA16(a1h, fB1h, z1b);
            z0a = MFMA16(a2h, fA2h, z0a);  z1a = MFMA16(a2h, fB2h, z1a);
            z0b = MFMA16(a0l, fA0h, z0b);  z1b = MFMA16(a0l, fB0h, z1b);
            z0a = MFMA16(a1l, fA1h, z0a);  z1a = MFMA16(a1l, fB1h, z1a);
            z0b = MFMA16(a2l, fA2h, z0b);  z1b = MFMA16(a2l, fB2h, z1b);
            z0a = MFMA16(a0h, fA0l, z0a);  z1a = MFMA16(a0h, fB0l, z1a);
            z0b = MFMA16(a1h, fA1l, z0b);  z1b = MFMA16(a1h, fB1l, z1b);
            z0a = MFMA16(a2h, fA2l, z0a);  z1a = MFMA16(a2h, fB2l, z1a);
            f32x4 z0 = z0a + z0b, z1 = z1a + z1b;
            lstm_gates(z0, z1, hbuf[p ^ 1], true, true);
        }
        BARRIER();   // B2: h_t + mlps.h visible

        if (!gA) mlp1();
        BARRIER();   // B3: hids visible

        if (!gA) {
            mlp2();
            out[((size_t)(b0 + l4 * 4 + 0) * 48 + t) * 64 + j1] = lat0;
            out[((size_t)(b0 + l4 * 4 + 1) * 48 + t) * 64 + j1] = lat1;
            out[((size_t)(b0 + l4 * 4 + 2) * 48 + t) * 64 + j1] = lat2;
            out[((size_t)(b0 + l4 * 4 + 3) * 48 + t) * 64 + j1] = lat3;
        } else {
            // A idle slot: stage cn/fc for iter t+1; prefetch control t+2
            int tn = (t < 47) ? t + 1 : 47;
            stage_cn(creg);
            stage_fc(tn);
            int tn2 = (t < 46) ? t + 2 : 47;
            if (lt < 64)
                creg = *(const f32x4*)(control + ((size_t)(b0 + rc) * 48 + tn2) * 16 + cc);
        }
    }
}

extern "C" void kernel_launch(void* const* d_in, const int* in_sizes, int n_in,
                              void* d_out, int out_size, void* d_ws, size_t ws_size,
                              hipStream_t stream) {
    tutina_kernel<<<dim3(256), dim3(512), 0, stream>>>(
        (const float*)d_in[0],  (const float*)d_in[1],  (const float*)d_in[2],
        (const float*)d_in[3],  (const float*)d_in[4],  (const float*)d_in[5],
        (const float*)d_in[6],  (const float*)d_in[7],  (const float*)d_in[8],
        (const float*)d_in[9],  (const float*)d_in[10], (const float*)d_in[11],
        (const float*)d_in[12], (const float*)d_in[13], (const float*)d_in[14],
        (const float*)d_in[15], (const float*)d_in[16], (const float*)d_in[17],
        (float*)d_out);
}